// Round 4
// baseline (97.432 us; speedup 1.0000x reference)
//
#include <hip/hip_runtime.h>
#include <math.h>

// Problem constants (match reference)
constexpr int BN = 128;
constexpr int FH = 26, FW = 26;
constexpr int T  = 50;
constexpr int A  = 5;
constexpr int NC = 20;
constexpr int K  = FH * FW;      // 676
constexpr int KA = K * A;        // 3380
constexpr int CH = A * (5 + NC); // 125

constexpr float IGNORE_THRESH = 0.75f;
constexpr float OBJ_SCALE = 5.0f;
// NOOBJ_SCALE = 1.0 (folded into the math)

constexpr int NG      = KA / 4;               // 845 float4 slot-groups per batch
constexpr int GCHUNKS = (NG + 255) / 256;     // 4 blocks of 256 per batch
constexpr int NPART   = BN * GCHUNKS;         // 512 partials

__constant__ float ANCW[A] = {1.3221f, 3.19275f, 5.05587f, 9.47112f, 11.2364f};
__constant__ float ANCH[A] = {1.73145f, 4.00944f, 8.09892f, 4.84053f, 10.0071f};

__device__ __forceinline__ float fast_sigmoid(float x) {
    return __builtin_amdgcn_rcpf(1.0f + __expf(-x));
}

// ---------------------------------------------------------------------------
// Main pass: grid (GCHUNKS, BN), 256 threads. Each thread owns FOUR adjacent
// slots (one float4 group along k; K%4==0 so a group never crosses an anchor
// plane). Pred-plane loads are aligned float4 (coalesced 1KB/wave) and the two
// DS broadcast reads per GT-iteration are amortized over 4 IoUs.
// Winner = last t whose assigned slot matches (== lax.scan overwrite).
// pos_any correction deferred: noobj term added unconditionally, the subset
// with m>=thresh also summed into Mp; fix kernel computes
//      out = [ sum_b (L_b - pany_b * M_b) ] / BN
// No atomics, no zero-init anywhere.
// ---------------------------------------------------------------------------
__global__ __launch_bounds__(256) void yolo_main(
        const float* __restrict__ outputs,   // (B, 125, 26, 26)
        const float* __restrict__ targets,   // (B, 50, 5)
        float* __restrict__ Lp, float* __restrict__ Mp, int* __restrict__ Anyp) {
    __shared__ float4 sbox[T];   // x1,y1,x2,y2 (degenerate if invalid)
    __shared__ float2 sas[T];    // area (1.0 if invalid), slot-as-int (-1 if invalid)
    __shared__ float4 stb[T];    // tb0..tb3
    __shared__ float  scls[T];
    __shared__ float  redl[4], redm[4];
    __shared__ int    reda[4];

    const int b   = blockIdx.y;
    const int tid = threadIdx.x;

    // ---- issue pred loads first (independent of LDS), overlap GT decode ----
    const int g      = blockIdx.x * 256 + tid;       // slot-group id
    const bool live  = g < NG;
    const int a      = live ? (g / 169) : 0;         // NG/ A = 169 groups/plane
    const int k0     = (g - a * 169) * 4;            // k of slot 0 in group
    const float* ob  = outputs + (size_t)b * CH * K + (size_t)(a * 25) * K;

    float4 o0, o1, o2, o3, o4;
    if (live) {
        o0 = *(const float4*)(ob + 0 * K + k0);
        o1 = *(const float4*)(ob + 1 * K + k0);
        o2 = *(const float4*)(ob + 2 * K + k0);
        o3 = *(const float4*)(ob + 3 * K + k0);
        o4 = *(const float4*)(ob + 4 * K + k0);
    }

    // ---- per-block GT decode (threads 0..T-1) ----
    if (tid < T) {
        const float* gt = targets + ((size_t)b * T + tid) * 5;
        float rx1 = gt[0], ry1 = gt[1], rx2 = gt[2], ry2 = gt[3];
        bool valid = (rx1 + ry1 + rx2 + ry2) > 0.0f;
        float x1 = rx1 * FW, y1 = ry1 * FH, x2 = rx2 * FW, y2 = ry2 * FH;
        float w = x2 - x1, h = y2 - y1;

        float cxf = 0.5f * (x1 + x2), cyf = 0.5f * (y1 + y2);
        int cx = (int)floorf(cxf); cx = min(max(cx, 0), FW - 1);
        int cy = (int)floorf(cyf); cy = min(max(cy, 0), FH - 1);
        int cell = cy * FW + cx;

        // argmax over anchors (first max wins) of IoU(anchor@cell-center, gt)
        float acx = (float)cx + 0.5f, acy = (float)cy + 0.5f;
        float best = -1.0f; int ai = 0;
        for (int aa = 0; aa < A; ++aa) {
            float aw = ANCW[aa], ah = ANCH[aa];
            float xi1 = fmaxf(acx - 0.5f * aw, x1), yi1 = fmaxf(acy - 0.5f * ah, y1);
            float xi2 = fminf(acx + 0.5f * aw, x2), yi2 = fminf(acy + 0.5f * ah, y2);
            float inter = fmaxf(xi2 - xi1, 0.0f) * fmaxf(yi2 - yi1, 0.0f);
            float iou = inter / (aw * ah + w * h - inter);
            if (iou > best) { best = iou; ai = aa; }
        }

        if (valid) {
            sbox[tid] = make_float4(x1, y1, x2, y2);
            sas[tid]  = make_float2(w * h, __int_as_float(ai * K + cell));
        } else {
            sbox[tid] = make_float4(1e18f, 1e18f, -1e18f, -1e18f);  // inter -> 0
            sas[tid]  = make_float2(1.0f, __int_as_float(-1));       // iou -> 0
        }
        stb[tid]  = make_float4(cxf - (float)cx, cyf - (float)cy,
                                w / ANCW[ai], h / ANCH[ai]);
        scls[tid] = gt[4];
    }
    __syncthreads();

    float loss = 0.0f, masked = 0.0f;
    int anyf = 0;

    if (live) {
        const int s0 = a * K + k0;   // slot id of lane's first sub-slot
        const float oo0[4] = {o0.x, o0.y, o0.z, o0.w};
        const float oo1[4] = {o1.x, o1.y, o1.z, o1.w};
        const float oo2[4] = {o2.x, o2.y, o2.z, o2.w};
        const float oo3[4] = {o3.x, o3.y, o3.z, o3.w};
        const float oo4[4] = {o4.x, o4.y, o4.z, o4.w};

        float s0v[4], s1v[4], e2v[4], e3v[4];
        float px1[4], px2[4], py1[4], py2[4], parea[4], mm[4];
        int   wi[4];
        #pragma unroll
        for (int j = 0; j < 4; ++j) {
            int k = k0 + j;
            int yy = k / FW, xx = k - yy * FW;
            s0v[j] = fast_sigmoid(oo0[j]);
            s1v[j] = fast_sigmoid(oo1[j]);
            e2v[j] = __expf(oo2[j]);
            e3v[j] = __expf(oo3[j]);
            float px = (float)xx + s0v[j], py = (float)yy + s1v[j];
            float pw = ANCW[a] * e2v[j],  ph = ANCH[a] * e3v[j];
            px1[j] = px - 0.5f * pw; px2[j] = px + 0.5f * pw;
            py1[j] = py - 0.5f * ph; py2[j] = py + 0.5f * ph;
            parea[j] = pw * ph;
            mm[j] = -1.0f;
            wi[j] = -1;
        }

        #pragma unroll 5
        for (int t = 0; t < T; ++t) {
            float4 bx  = sbox[t];
            float2 as2 = sas[t];
            int slot_t = __float_as_int(as2.y);
            #pragma unroll
            for (int j = 0; j < 4; ++j) {
                float xi1 = fmaxf(px1[j], bx.x), yi1 = fmaxf(py1[j], bx.y);
                float xi2 = fminf(px2[j], bx.z), yi2 = fminf(py2[j], bx.w);
                float iw = fmaxf(xi2 - xi1, 0.0f), ih = fmaxf(yi2 - yi1, 0.0f);
                float inter = iw * ih;
                float iou = inter * __builtin_amdgcn_rcpf(parea[j] + as2.x - inter);
                mm[j] = fmaxf(mm[j], iou);
                if (slot_t == s0 + j) wi[j] = t;   // ascending t => last wins
            }
        }

        #pragma unroll
        for (int j = 0; j < 4; ++j) {
            float m = mm[j];
            anyf |= (m > IGNORE_THRESH) ? 1 : 0;
            float conf = fast_sigmoid(oo4[j]);
            int w = wi[j];
            if (w >= 0) {
                // assigned: conf MSE at OBJ scale + box MSE + class CE
                float d = (conf - m) * OBJ_SCALE;
                loss += 0.5f * d * d;
                float4 tb = stb[w];
                float d0 = s0v[j] - tb.x, d1 = s1v[j] - tb.y;
                float d2 = e2v[j] - tb.z, d3 = e3v[j] - tb.w;
                loss += 0.5f * (d0 * d0 + d1 * d1 + d2 * d2 + d3 * d3);

                float v[NC];
                #pragma unroll
                for (int c = 0; c < NC; ++c) v[c] = ob[(5 + c) * K + k0 + j];
                float mx = v[0];
                #pragma unroll
                for (int c = 1; c < NC; ++c) mx = fmaxf(mx, v[c]);
                float se = 0.0f;
                #pragma unroll
                for (int c = 0; c < NC; ++c) se += __expf(v[c] - mx);
                int cls = (int)scls[w];
                loss += (__logf(se) + mx) - v[cls];
            } else {
                // unassigned: noobj term (NOOBJ_SCALE=1); cancelled later if pos_any
                float term = 0.5f * conf * conf;
                loss += term;
                if (m >= IGNORE_THRESH) masked += term;
            }
        }
    }

    // ---- block reduce ----
    for (int off = 32; off > 0; off >>= 1) {
        loss   += __shfl_down(loss, off);
        masked += __shfl_down(masked, off);
    }
    anyf = __any(anyf) ? 1 : 0;
    int lane = tid & 63, wv = tid >> 6;
    if (lane == 0) { redl[wv] = loss; redm[wv] = masked; reda[wv] = anyf; }
    __syncthreads();
    if (tid == 0) {
        int idx = b * GCHUNKS + blockIdx.x;
        Lp[idx]   = redl[0] + redl[1] + redl[2] + redl[3];
        Mp[idx]   = redm[0] + redm[1] + redm[2] + redm[3];
        Anyp[idx] = reda[0] | reda[1] | reda[2] | reda[3];
    }
}

// ---------------------------------------------------------------------------
// Fix/reduce: thread b folds its chunk-partials, applies the pos_any
// correction, block-reduces 128 values, single plain store of the scalar.
// ---------------------------------------------------------------------------
__global__ __launch_bounds__(128) void yolo_fix(
        const float* __restrict__ Lp, const float* __restrict__ Mp,
        const int* __restrict__ Anyp, float* __restrict__ out) {
    __shared__ float red[2];
    int tid = threadIdx.x;
    float L = 0.0f, M = 0.0f;
    int any = 0;
    if (tid < BN) {
        #pragma unroll
        for (int c = 0; c < GCHUNKS; ++c) {
            int idx = tid * GCHUNKS + c;
            L += Lp[idx];
            M += Mp[idx];
            any |= Anyp[idx];
        }
    }
    float acc = L - (any ? M : 0.0f);
    for (int off = 32; off > 0; off >>= 1) acc += __shfl_down(acc, off);
    if ((tid & 63) == 0) red[tid >> 6] = acc;
    __syncthreads();
    if (tid == 0) out[0] = (red[0] + red[1]) * (1.0f / (float)BN);
}

extern "C" void kernel_launch(void* const* d_in, const int* in_sizes, int n_in,
                              void* d_out, int out_size, void* d_ws, size_t ws_size,
                              hipStream_t stream) {
    const float* outputs = (const float*)d_in[0];
    const float* targets = (const float*)d_in[1];
    float* out = (float*)d_out;

    // ws layout: Lp[512] | Mp[512] | Anyp[512]  (~6 KB, written before read)
    float* Lp   = (float*)d_ws;
    float* Mp   = Lp + NPART;
    int*   Anyp = (int*)(Mp + NPART);

    yolo_main<<<dim3(GCHUNKS, BN), 256, 0, stream>>>(outputs, targets, Lp, Mp, Anyp);
    yolo_fix<<<1, 128, 0, stream>>>(Lp, Mp, Anyp, out);
}